// Round 18
// baseline (238.431 us; speedup 1.0000x reference)
//
#include <hip/hip_runtime.h>
#include <hip/hip_bf16.h>
#include <math.h>

typedef __hip_bfloat16 bf16;
typedef __attribute__((ext_vector_type(8))) short bf16x8;
typedef __attribute__((ext_vector_type(4))) float f32x4;

#define B_   256
#define NPG_ 200
#define N0_  (B_*NPG_)
#define DEGC 16
#define SLOTG (NPG_*DEGC)   // 3200 edge slots per graph (original layout)
#define FIN_ 128
#define H_   256
#define NTHR 768

// ---- LDS arena layout (bytes) ----
#define ARENA_OFF   0           // float[26400]: X [200][132] or pooled [k][260]
#define BSLAB_OFF   105600      // bf16 hi[8192] + lo[8192]
#define CSRCL_OFF   138368      // ushort[3200]
#define OFFSL_OFF   144768      // int[256]
#define OFFEL_OFF   145792      // int[256]
#define DV_OFF      146816      // float[256]
#define CNT_OFF     147840      // int[256]
#define SCN_OFF     148864      // int[256]
#define POS_OFF     149888      // int[256]
#define CML_OFF     150912      // int[256]
#define XSL_OFF     151936      // float[256]
#define SCO_OFF     152960      // float[256]
#define IDX_OFF     153984      // int[256]
#define RL_OFF      155008      // int[256]
#define TS_OFF      156032      // float[128]
#define ZLDS_OFF    156544      // float[512]
#define LDS_TOTAL   158592

__device__ __forceinline__ unsigned int bfu(bf16 h) {
    return (unsigned int)*reinterpret_cast<unsigned short*>(&h);
}

__device__ __forceinline__ void split8(const float a[8], bf16x8& ah, bf16x8& al) {
    #pragma unroll
    for (int i = 0; i < 8; i++) {
        float v = a[i];
        bf16 h = __float2bfloat16(v);
        float rem = v - __bfloat162float(h);
        bf16 l = __float2bfloat16(rem);
        ah[i] = (short)bfu(h);
        al[i] = (short)bfu(l);
    }
}

// ---- batched W convert: W[K][N] f32 -> WT hi/lo bf16 [N][K], all 3 stages ----
__global__ void wconv_k(const float* __restrict__ W1, const float* __restrict__ W2,
                        const float* __restrict__ W3, bf16* __restrict__ THb,
                        bf16* __restrict__ TLb) {
    __shared__ float tile[32][33];
    int st = blockIdx.z;
    const float* W = st == 0 ? W1 : (st == 1 ? W2 : W3);
    int K = st == 0 ? 128 : 256;
    int N = 256;
    int k0 = blockIdx.x * 32, n0 = blockIdx.y * 32;
    if (k0 >= K) return;
    bf16* TH = THb + st * 65536;
    bf16* TL = TLb + st * 65536;
    int t = threadIdx.x;
    int tc = t & 31, tr = t >> 5;
    #pragma unroll
    for (int i = 0; i < 4; i++) {
        int kk = tr + i * 8;
        tile[kk][tc] = W[(size_t)(k0 + kk) * N + n0 + tc];
    }
    __syncthreads();
    #pragma unroll
    for (int i = 0; i < 4; i++) {
        int nn = tr + i * 8;
        float v = tile[tc][nn];
        bf16 h = __float2bfloat16(v);
        TH[(size_t)(n0 + nn) * K + k0 + tc] = h;
        TL[(size_t)(n0 + nn) * K + k0 + tc] = __float2bfloat16(v - __bfloat162float(h));
    }
}

// ---- mega kernel: one block per graph, 768 threads (12 waves, 3/SIMD) ----
__global__ __launch_bounds__(NTHR) void mega_k(
        const float* __restrict__ X, const int* __restrict__ esrc, const int* __restrict__ edst,
        const bf16* __restrict__ WTH, const bf16* __restrict__ WTL,
        const float* __restrict__ b1, const float* __restrict__ b2, const float* __restrict__ b3,
        const float* __restrict__ Ws1, const float* __restrict__ Ws2, const float* __restrict__ Ws3,
        const float* __restrict__ bs1, const float* __restrict__ bs2, const float* __restrict__ bs3,
        const float* __restrict__ Wl1, const float* __restrict__ bl1,
        const float* __restrict__ Wl2, const float* __restrict__ bl2,
        const float* __restrict__ Wl3, const float* __restrict__ bl3,
        float* __restrict__ out) {
    extern __shared__ char lds[];
    float*          arena = (float*)(lds + ARENA_OFF);
    bf16*           lBhi  = (bf16*)(lds + BSLAB_OFF);
    bf16*           lBlo  = lBhi + 8192;
    unsigned short* csrcL = (unsigned short*)(lds + CSRCL_OFF);
    int*            offsL = (int*)(lds + OFFSL_OFF);
    int*            offeL = (int*)(lds + OFFEL_OFF);
    float*          dv    = (float*)(lds + DV_OFF);
    int*            cnt   = (int*)(lds + CNT_OFF);
    int*            scn   = (int*)(lds + SCN_OFF);
    int*            pos   = (int*)(lds + POS_OFF);
    int*            cml   = (int*)(lds + CML_OFF);
    float*          xsl   = (float*)(lds + XSL_OFF);
    float*          sco   = (float*)(lds + SCO_OFF);
    int*            idx   = (int*)(lds + IDX_OFF);
    int*            rl    = (int*)(lds + RL_OFF);
    float*          ts    = (float*)(lds + TS_OFF);
    float*          zlds  = (float*)(lds + ZLDS_OFF);

    int g = blockIdx.x;
    int t = threadIdx.x;
    int w = t >> 6, lane = t & 63;
    int coll = lane & 15, kgq = lane >> 4;
    int ob0 = g * NPG_;
    int ebase = g * SLOTG;

    if (t < 512) zlds[t] = 0.0f;
    if (t < 256) cml[t] = (t < NPG_) ? t : -1;

    // stage-0 X load: [200][128] f32 -> arena stride 132 (33 float4/row)
    {
        const float4* src = (const float4*)(X + (size_t)ob0 * FIN_);
        float4* dst = (float4*)arena;
        for (int i = t; i < NPG_ * 32; i += NTHR) {
            int row = i >> 5, c4 = i & 31;
            dst[row * 33 + c4] = src[i];
        }
    }

    for (int st = 0; st < 3; st++) {
        const int npg = (st == 0) ? 200 : (st == 1 ? 100 : 50);
        const int kA  = (st == 0) ? 100 : (st == 1 ? 50 : 25);
        const int FI  = (st == 0) ? 128 : 256;
        const int MT  = (st == 0) ? 13 : (st == 1 ? 7 : 4);
        const int strideF = (st == 0) ? 132 : 260;
        const int KS  = FI / 32;
        const bf16* BTH = WTH + st * 65536;
        const bf16* BTL = WTL + st * 65536;
        const float* bias = (st == 0) ? b1 : (st == 1 ? b2 : b3);
        const float* Wsd  = (st == 0) ? Ws1 : (st == 1 ? Ws2 : Ws3);
        const float* bsp  = (st == 0) ? bs1 : (st == 1 ? bs2 : bs3);

        if (t < 256) { cnt[t] = 0; rl[t] = -1; }
        __syncthreads();

        // ---- edge pass 1: degree count (via cml) ----
        for (int e = t; e < SLOTG; e += NTHR) {
            int cs = cml[esrc[ebase + e] - ob0];
            int cd = cml[edst[ebase + e] - ob0];
            if (cs >= 0 && cd >= 0) atomicAdd(&cnt[cd], 1);
        }
        __syncthreads();

        // ---- scan (exclusive) + dv ----
        int v = 0;
        if (t < 256) {
            v = (t < npg) ? cnt[t] : 0;
            dv[t] = rsqrtf((float)v + 1.0f);
            scn[t] = v;
        }
        __syncthreads();
        for (int d = 1; d < 256; d <<= 1) {
            int u = (t < 256 && t >= d) ? scn[t - d] : 0;
            __syncthreads();
            if (t < 256) scn[t] += u;
            __syncthreads();
        }
        if (t < 256) {
            int excl = scn[t] - v;
            offsL[t] = excl; offeL[t] = excl + v; pos[t] = excl;
        }
        __syncthreads();

        // ---- edge pass 2: scatter local src ids ----
        for (int e = t; e < SLOTG; e += NTHR) {
            int cs = cml[esrc[ebase + e] - ob0];
            int cd = cml[edst[ebase + e] - ob0];
            if (cs >= 0 && cd >= 0) {
                int p = atomicAdd(&pos[cd], 1);
                csrcL[p] = (unsigned short)cs;
            }
        }
        __syncthreads();

        // ---- GEMM: h = relu(Agg(X) @ W + bias); agg fused into A-frag load ----
        f32x4 acc[2][16] = {};
        for (int ks = 0; ks < KS; ks++) {
            // stage B k-slab (hi+lo) cooperatively: chunk-major [kg][col][8]
            for (int c = t; c < 2048; c += NTHR) {
                int arr = c >> 10, id2 = c & 1023;
                int col = id2 >> 2, kg = id2 & 3;
                const bf16* src = (arr ? BTL : BTH) + (size_t)col * FI + ks * 32 + kg * 8;
                bf16* dst = (arr ? lBlo : lBhi) + kg * 2048 + col * 8;
                *(uint4*)dst = *(const uint4*)src;
            }
            __syncthreads();
            #pragma unroll
            for (int rep = 0; rep < 2; rep++) {
                int mt = w + rep * 12;
                if (mt < MT) {
                    int rL = mt * 16 + coll;
                    int kbase = ks * 32 + kgq * 8;
                    float a8[8] = {0.f,0.f,0.f,0.f,0.f,0.f,0.f,0.f};
                    if (rL < npg) {
                        float ddv = dv[rL];
                        int e0 = offsL[rL], e1 = offeL[rL];
                        for (int j = e0; j < e1; j++) {
                            int s = csrcL[j];
                            float cf = ddv * dv[s];
                            const float* xr = arena + s * strideF + kbase;
                            float4 xa = *(const float4*)xr;
                            float4 xb = *(const float4*)(xr + 4);
                            a8[0] += cf * xa.x; a8[1] += cf * xa.y;
                            a8[2] += cf * xa.z; a8[3] += cf * xa.w;
                            a8[4] += cf * xb.x; a8[5] += cf * xb.y;
                            a8[6] += cf * xb.z; a8[7] += cf * xb.w;
                        }
                        float cf = ddv * ddv;
                        const float* xr = arena + rL * strideF + kbase;
                        float4 xa = *(const float4*)xr;
                        float4 xb = *(const float4*)(xr + 4);
                        a8[0] += cf * xa.x; a8[1] += cf * xa.y;
                        a8[2] += cf * xa.z; a8[3] += cf * xa.w;
                        a8[4] += cf * xb.x; a8[5] += cf * xb.y;
                        a8[6] += cf * xb.z; a8[7] += cf * xb.w;
                    }
                    bf16x8 ah, al;
                    split8(a8, ah, al);
                    #pragma unroll
                    for (int nt = 0; nt < 16; nt++) {
                        int col = nt * 16 + coll;
                        bf16x8 bh = *(const bf16x8*)&lBhi[kgq * 2048 + col * 8];
                        bf16x8 bl = *(const bf16x8*)&lBlo[kgq * 2048 + col * 8];
                        acc[rep][nt] = __builtin_amdgcn_mfma_f32_16x16x32_bf16(ah, bh, acc[rep][nt], 0, 0, 0);
                        acc[rep][nt] = __builtin_amdgcn_mfma_f32_16x16x32_bf16(ah, bl, acc[rep][nt], 0, 0, 0);
                        acc[rep][nt] = __builtin_amdgcn_mfma_f32_16x16x32_bf16(al, bh, acc[rep][nt], 0, 0, 0);
                    }
                }
            }
            __syncthreads();
        }

        // ---- epilogue: bias + relu in place, xs = h.Ws ----
        #pragma unroll
        for (int rep = 0; rep < 2; rep++) {
            int mt = w + rep * 12;
            if (mt < MT) {
                float pr[4] = {0.f, 0.f, 0.f, 0.f};
                #pragma unroll
                for (int nt = 0; nt < 16; nt++) {
                    int col = nt * 16 + coll;
                    float bv = bias[col];
                    float wsv = Wsd[col];
                    #pragma unroll
                    for (int r = 0; r < 4; r++) {
                        float hv = fmaxf(acc[rep][nt][r] + bv, 0.0f);
                        acc[rep][nt][r] = hv;
                        pr[r] += hv * wsv;
                    }
                }
                #pragma unroll
                for (int r = 0; r < 4; r++) {
                    pr[r] += __shfl_xor(pr[r], 1); pr[r] += __shfl_xor(pr[r], 2);
                    pr[r] += __shfl_xor(pr[r], 4); pr[r] += __shfl_xor(pr[r], 8);
                }
                if (coll == 0) {
                    #pragma unroll
                    for (int r = 0; r < 4; r++) {
                        int rloc = mt * 16 + kgq * 4 + r;
                        if (rloc < npg) xsl[rloc] = pr[r];
                    }
                }
            }
        }
        __syncthreads();

        // ---- score GCN ----
        if (t < 256) {
            float scv = -INFINITY;
            if (t < npg) {
                float dd = dv[t];
                float a = 0.f;
                for (int j = offsL[t]; j < offeL[t]; j++) {
                    int s = csrcL[j];
                    a += dd * dv[s] * xsl[s];
                }
                scv = a + xsl[t] * dd * dd + bsp[0];
            }
            sco[t] = scv;
            idx[t] = (t < npg) ? t : 0x7fffffff;
        }
        __syncthreads();

        // ---- bitonic top-k sort by (-score, idx) ----
        for (int ksz = 2; ksz <= 256; ksz <<= 1) {
            for (int j = ksz >> 1; j > 0; j >>= 1) {
                int ixj = t ^ j;
                if (t < 256 && ixj > t) {
                    float s1 = sco[t], s2 = sco[ixj];
                    int i1 = idx[t], i2 = idx[ixj];
                    bool asc = ((t & ksz) == 0);
                    bool agtb = (s1 < s2) || (s1 == s2 && i1 > i2);
                    if (asc ? agtb : !agtb) { sco[t] = s2; sco[ixj] = s1; idx[t] = i2; idx[ixj] = i1; }
                }
                __syncthreads();
            }
        }
        if (t < kA) {
            rl[idx[t]] = t;
            ts[t] = tanhf(sco[t]);
        }
        __syncthreads();

        // ---- cml compose + pooling from acc regs into arena (stride 260) ----
        if (t < 256) {
            int old = cml[t];
            cml[t] = (old >= 0) ? rl[old] : -1;
        }
        #pragma unroll
        for (int rep = 0; rep < 2; rep++) {
            int mt = w + rep * 12;
            if (mt < MT) {
                #pragma unroll
                for (int r = 0; r < 4; r++) {
                    int rloc = mt * 16 + kgq * 4 + r;
                    int slot = (rloc < npg) ? rl[rloc] : -1;
                    if (slot >= 0) {
                        float tg = ts[slot];
                        #pragma unroll
                        for (int nt = 0; nt < 16; nt++)
                            arena[slot * 260 + nt * 16 + coll] = acc[rep][nt][r] * tg;
                    }
                }
            }
        }
        __syncthreads();

        // ---- readout gmp||gap into zlds ----
        if (t < 256) {
            float mx = -INFINITY, sm = 0.f;
            for (int j = 0; j < kA; j++) {
                float hv = arena[j * 260 + t];
                mx = fmaxf(mx, hv); sm += hv;
            }
            zlds[t] += mx;
            zlds[256 + t] += sm / (float)kA;
        }
        __syncthreads();
    }

    // ---- MLP head + log_softmax (reuse xsl as h1, sco as h2) ----
    float* h1 = xsl;
    float* h2 = sco;
    if (t < 256) {
        float a = bl1[t];
        for (int k = 0; k < 512; k++) a += zlds[k] * Wl1[k * 256 + t];
        h1[t] = fmaxf(a, 0.f);
    }
    __syncthreads();
    if (t < 128) {
        float a = bl2[t];
        for (int k = 0; k < 256; k++) a += h1[k] * Wl2[k * 128 + t];
        h2[t] = fmaxf(a, 0.f);
    }
    __syncthreads();
    if (t < 64) {
        float a0 = h2[t], a1 = h2[t + 64];
        float r[10];
        #pragma unroll
        for (int n = 0; n < 10; n++) r[n] = a0 * Wl3[t * 10 + n] + a1 * Wl3[(t + 64) * 10 + n];
        #pragma unroll
        for (int d = 1; d < 64; d <<= 1)
            #pragma unroll
            for (int n = 0; n < 10; n++) r[n] += __shfl_xor(r[n], d);
        float vv[10]; float mxv = -INFINITY;
        #pragma unroll
        for (int n = 0; n < 10; n++) { vv[n] = r[n] + bl3[n]; mxv = fmaxf(mxv, vv[n]); }
        float s = 0.f;
        #pragma unroll
        for (int n = 0; n < 10; n++) s += expf(vv[n] - mxv);
        float ls = logf(s);
        if (t < 10) out[g * 10 + t] = vv[t] - mxv - ls;
    }
}

extern "C" void kernel_launch(void* const* d_in, const int* in_sizes, int n_in,
                              void* d_out, int out_size, void* d_ws, size_t ws_size,
                              hipStream_t stream) {
    const float* x   = (const float*)d_in[0];
    const int*  esrc = (const int*) d_in[1];
    const int*  edst = (const int*) d_in[2];
    const float *W1 = (const float*)d_in[3],  *b1 = (const float*)d_in[4];
    const float *Ws1= (const float*)d_in[5],  *bs1= (const float*)d_in[6];
    const float *W2 = (const float*)d_in[7],  *b2 = (const float*)d_in[8];
    const float *Ws2= (const float*)d_in[9],  *bs2= (const float*)d_in[10];
    const float *W3 = (const float*)d_in[11], *b3 = (const float*)d_in[12];
    const float *Ws3= (const float*)d_in[13], *bs3= (const float*)d_in[14];
    const float *Wl1= (const float*)d_in[15], *bl1= (const float*)d_in[16];
    const float *Wl2= (const float*)d_in[17], *bl2= (const float*)d_in[18];
    const float *Wl3= (const float*)d_in[19], *bl3= (const float*)d_in[20];
    float* out = (float*)d_out;

    bf16* WTH = (bf16*)d_ws;                 // 3 * 256*256 bf16
    bf16* WTL = WTH + 3 * 65536;             // 3 * 256*256 bf16

    // 1. weight convert (all 3 stages)
    wconv_k<<<dim3(8, 8, 3), 256, 0, stream>>>(W1, W2, W3, WTH, WTL);

    // 2. whole network, one block per graph
    mega_k<<<B_, NTHR, LDS_TOTAL, stream>>>(
        x, esrc, edst, WTH, WTL,
        b1, b2, b3, Ws1, Ws2, Ws3, bs1, bs2, bs3,
        Wl1, bl1, Wl2, bl2, Wl3, bl3, out);
}

// Round 19
// 162.980 us; speedup vs baseline: 1.4629x; 1.4629x over previous
//
#include <hip/hip_runtime.h>
#include <hip/hip_bf16.h>
#include <math.h>

typedef __hip_bfloat16 bf16;
typedef __attribute__((ext_vector_type(8))) short bf16x8;
typedef __attribute__((ext_vector_type(4))) float f32x4;

#define B_   256
#define NPG_ 200
#define N0_  (B_*NPG_)
#define DEGC 16
#define SLOTG (NPG_*DEGC)   // 3200 edge slots per graph (original layout)
#define FIN_ 128
#define H_   256

// ---- LDS arena layout (bytes) ----
#define ARENA_OFF   0           // float[26400]: X [200][132] or pooled [k][260]
#define BSLAB_OFF   105600      // bf16 hi[8192] + lo[8192]
#define CSRCL_OFF   138368      // ushort[3200]
#define OFFSL_OFF   144768      // int[256]
#define OFFEL_OFF   145792      // int[256]
#define DV_OFF      146816      // float[256]
#define CNT_OFF     147840      // int[256]
#define SCN_OFF     148864      // int[256]
#define POS_OFF     149888      // int[256]
#define CML_OFF     150912      // int[256]
#define XSL_OFF     151936      // float[256]
#define SCO_OFF     152960      // float[256]
#define IDX_OFF     153984      // int[256]
#define RL_OFF      155008      // int[256]
#define TS_OFF      156032      // float[128]
#define ZLDS_OFF    156544      // float[512]
#define LDS_TOTAL   158592

__device__ __forceinline__ unsigned int bfu(bf16 h) {
    return (unsigned int)*reinterpret_cast<unsigned short*>(&h);
}

__device__ __forceinline__ void split8(const float a[8], bf16x8& ah, bf16x8& al) {
    #pragma unroll
    for (int i = 0; i < 8; i++) {
        float v = a[i];
        bf16 h = __float2bfloat16(v);
        float rem = v - __bfloat162float(h);
        bf16 l = __float2bfloat16(rem);
        ah[i] = (short)bfu(h);
        al[i] = (short)bfu(l);
    }
}

// ---- batched W convert: W[K][N] f32 -> WT hi/lo bf16 [N][K], all 3 stages ----
__global__ void wconv_k(const float* __restrict__ W1, const float* __restrict__ W2,
                        const float* __restrict__ W3, bf16* __restrict__ THb,
                        bf16* __restrict__ TLb) {
    __shared__ float tile[32][33];
    int st = blockIdx.z;
    const float* W = st == 0 ? W1 : (st == 1 ? W2 : W3);
    int K = st == 0 ? 128 : 256;
    int N = 256;
    int k0 = blockIdx.x * 32, n0 = blockIdx.y * 32;
    if (k0 >= K) return;
    bf16* TH = THb + st * 65536;
    bf16* TL = TLb + st * 65536;
    int t = threadIdx.x;
    int tc = t & 31, tr = t >> 5;
    #pragma unroll
    for (int i = 0; i < 4; i++) {
        int kk = tr + i * 8;
        tile[kk][tc] = W[(size_t)(k0 + kk) * N + n0 + tc];
    }
    __syncthreads();
    #pragma unroll
    for (int i = 0; i < 4; i++) {
        int nn = tr + i * 8;
        float v = tile[tc][nn];
        bf16 h = __float2bfloat16(v);
        TH[(size_t)(n0 + nn) * K + k0 + tc] = h;
        TL[(size_t)(n0 + nn) * K + k0 + tc] = __float2bfloat16(v - __bfloat162float(h));
    }
}

// ---- the mega kernel: one block per graph, full network (proven r13 shape) ----
__global__ __launch_bounds__(512) void mega_k(
        const float* __restrict__ X, const int* __restrict__ esrc, const int* __restrict__ edst,
        const bf16* __restrict__ WTH, const bf16* __restrict__ WTL,
        const float* __restrict__ b1, const float* __restrict__ b2, const float* __restrict__ b3,
        const float* __restrict__ Ws1, const float* __restrict__ Ws2, const float* __restrict__ Ws3,
        const float* __restrict__ bs1, const float* __restrict__ bs2, const float* __restrict__ bs3,
        const float* __restrict__ Wl1, const float* __restrict__ bl1,
        const float* __restrict__ Wl2, const float* __restrict__ bl2,
        const float* __restrict__ Wl3, const float* __restrict__ bl3,
        float* __restrict__ out) {
    extern __shared__ char lds[];
    float*          arena = (float*)(lds + ARENA_OFF);
    bf16*           lBhi  = (bf16*)(lds + BSLAB_OFF);
    bf16*           lBlo  = lBhi + 8192;
    unsigned short* csrcL = (unsigned short*)(lds + CSRCL_OFF);
    int*            offsL = (int*)(lds + OFFSL_OFF);
    int*            offeL = (int*)(lds + OFFEL_OFF);
    float*          dv    = (float*)(lds + DV_OFF);
    int*            cnt   = (int*)(lds + CNT_OFF);
    int*            scn   = (int*)(lds + SCN_OFF);
    int*            pos   = (int*)(lds + POS_OFF);
    int*            cml   = (int*)(lds + CML_OFF);
    float*          xsl   = (float*)(lds + XSL_OFF);
    float*          sco   = (float*)(lds + SCO_OFF);
    int*            idx   = (int*)(lds + IDX_OFF);
    int*            rl    = (int*)(lds + RL_OFF);
    float*          ts    = (float*)(lds + TS_OFF);
    float*          zlds  = (float*)(lds + ZLDS_OFF);

    int g = blockIdx.x;
    int t = threadIdx.x;
    int w = t >> 6, lane = t & 63;
    int coll = lane & 15, kgq = lane >> 4;
    int ob0 = g * NPG_;
    int ebase = g * SLOTG;

    zlds[t] = 0.0f;
    if (t < 256) cml[t] = (t < NPG_) ? t : -1;

    // stage-0 X load: [200][128] f32 -> arena stride 132 (33 float4/row)
    {
        const float4* src = (const float4*)(X + (size_t)ob0 * FIN_);
        float4* dst = (float4*)arena;
        for (int i = t; i < NPG_ * 32; i += 512) {
            int row = i >> 5, c4 = i & 31;
            dst[row * 33 + c4] = src[i];
        }
    }

    for (int st = 0; st < 3; st++) {
        const int npg = (st == 0) ? 200 : (st == 1 ? 100 : 50);
        const int kA  = (st == 0) ? 100 : (st == 1 ? 50 : 25);
        const int FI  = (st == 0) ? 128 : 256;
        const int MT  = (st == 0) ? 13 : (st == 1 ? 7 : 4);
        const int strideF = (st == 0) ? 132 : 260;
        const int KS  = FI / 32;
        const bf16* BTH = WTH + st * 65536;
        const bf16* BTL = WTL + st * 65536;
        const float* bias = (st == 0) ? b1 : (st == 1 ? b2 : b3);
        const float* Wsd  = (st == 0) ? Ws1 : (st == 1 ? Ws2 : Ws3);
        const float* bsp  = (st == 0) ? bs1 : (st == 1 ? bs2 : bs3);

        if (t < 256) { cnt[t] = 0; rl[t] = -1; }
        __syncthreads();

        // ---- edge pass 1: degree count (via cml) ----
        for (int e = t; e < SLOTG; e += 512) {
            int cs = cml[esrc[ebase + e] - ob0];
            int cd = cml[edst[ebase + e] - ob0];
            if (cs >= 0 && cd >= 0) atomicAdd(&cnt[cd], 1);
        }
        __syncthreads();

        // ---- scan (exclusive) + dv ----
        int v = 0;
        if (t < 256) {
            v = (t < npg) ? cnt[t] : 0;
            dv[t] = rsqrtf((float)v + 1.0f);
            scn[t] = v;
        }
        __syncthreads();
        for (int d = 1; d < 256; d <<= 1) {
            int u = (t < 256 && t >= d) ? scn[t - d] : 0;
            __syncthreads();
            if (t < 256) scn[t] += u;
            __syncthreads();
        }
        if (t < 256) {
            int excl = scn[t] - v;
            offsL[t] = excl; offeL[t] = excl + v; pos[t] = excl;
        }
        __syncthreads();

        // ---- edge pass 2: scatter local src ids ----
        for (int e = t; e < SLOTG; e += 512) {
            int cs = cml[esrc[ebase + e] - ob0];
            int cd = cml[edst[ebase + e] - ob0];
            if (cs >= 0 && cd >= 0) {
                int p = atomicAdd(&pos[cd], 1);
                csrcL[p] = (unsigned short)cs;
            }
        }
        __syncthreads();

        // ---- GEMM: h = relu(Agg(X) @ W + bias); agg fused into A-frag load ----
        f32x4 acc[2][16] = {};
        for (int ks = 0; ks < KS; ks++) {
            // stage B k-slab (hi+lo) cooperatively: chunk-major [kg][col][8]
            for (int it = 0; it < 4; it++) {
                int c = t + it * 512;          // 0..2047
                int arr = c >> 10, id2 = c & 1023;
                int col = id2 >> 2, kg = id2 & 3;
                const bf16* src = (arr ? BTL : BTH) + (size_t)col * FI + ks * 32 + kg * 8;
                bf16* dst = (arr ? lBlo : lBhi) + kg * 2048 + col * 8;
                *(uint4*)dst = *(const uint4*)src;
            }
            __syncthreads();
            #pragma unroll
            for (int rep = 0; rep < 2; rep++) {
                int mt = w + rep * 8;
                if (mt < MT) {
                    int rL = mt * 16 + coll;
                    int kbase = ks * 32 + kgq * 8;
                    float a8[8] = {0.f,0.f,0.f,0.f,0.f,0.f,0.f,0.f};
                    if (rL < npg) {
                        float ddv = dv[rL];
                        int e0 = offsL[rL], e1 = offeL[rL];
                        for (int j = e0; j < e1; j++) {
                            int s = csrcL[j];
                            float cf = ddv * dv[s];
                            const float* xr = arena + s * strideF + kbase;
                            float4 xa = *(const float4*)xr;
                            float4 xb = *(const float4*)(xr + 4);
                            a8[0] += cf * xa.x; a8[1] += cf * xa.y;
                            a8[2] += cf * xa.z; a8[3] += cf * xa.w;
                            a8[4] += cf * xb.x; a8[5] += cf * xb.y;
                            a8[6] += cf * xb.z; a8[7] += cf * xb.w;
                        }
                        float cf = ddv * ddv;
                        const float* xr = arena + rL * strideF + kbase;
                        float4 xa = *(const float4*)xr;
                        float4 xb = *(const float4*)(xr + 4);
                        a8[0] += cf * xa.x; a8[1] += cf * xa.y;
                        a8[2] += cf * xa.z; a8[3] += cf * xa.w;
                        a8[4] += cf * xb.x; a8[5] += cf * xb.y;
                        a8[6] += cf * xb.z; a8[7] += cf * xb.w;
                    }
                    bf16x8 ah, al;
                    split8(a8, ah, al);
                    #pragma unroll
                    for (int nt = 0; nt < 16; nt++) {
                        int col = nt * 16 + coll;
                        bf16x8 bh = *(const bf16x8*)&lBhi[kgq * 2048 + col * 8];
                        bf16x8 bl = *(const bf16x8*)&lBlo[kgq * 2048 + col * 8];
                        acc[rep][nt] = __builtin_amdgcn_mfma_f32_16x16x32_bf16(ah, bh, acc[rep][nt], 0, 0, 0);
                        acc[rep][nt] = __builtin_amdgcn_mfma_f32_16x16x32_bf16(ah, bl, acc[rep][nt], 0, 0, 0);
                        acc[rep][nt] = __builtin_amdgcn_mfma_f32_16x16x32_bf16(al, bh, acc[rep][nt], 0, 0, 0);
                    }
                }
            }
            __syncthreads();
        }

        // ---- epilogue: bias + relu in place, xs = h.Ws ----
        #pragma unroll
        for (int rep = 0; rep < 2; rep++) {
            int mt = w + rep * 8;
            if (mt < MT) {
                float pr[4] = {0.f, 0.f, 0.f, 0.f};
                #pragma unroll
                for (int nt = 0; nt < 16; nt++) {
                    int col = nt * 16 + coll;
                    float bv = bias[col];
                    float wsv = Wsd[col];
                    #pragma unroll
                    for (int r = 0; r < 4; r++) {
                        float hv = fmaxf(acc[rep][nt][r] + bv, 0.0f);
                        acc[rep][nt][r] = hv;
                        pr[r] += hv * wsv;
                    }
                }
                #pragma unroll
                for (int r = 0; r < 4; r++) {
                    pr[r] += __shfl_xor(pr[r], 1); pr[r] += __shfl_xor(pr[r], 2);
                    pr[r] += __shfl_xor(pr[r], 4); pr[r] += __shfl_xor(pr[r], 8);
                }
                if (coll == 0) {
                    #pragma unroll
                    for (int r = 0; r < 4; r++) {
                        int rloc = mt * 16 + kgq * 4 + r;
                        if (rloc < npg) xsl[rloc] = pr[r];
                    }
                }
            }
        }
        __syncthreads();

        // ---- score GCN ----
        if (t < 256) {
            float scv = -INFINITY;
            if (t < npg) {
                float dd = dv[t];
                float a = 0.f;
                for (int j = offsL[t]; j < offeL[t]; j++) {
                    int s = csrcL[j];
                    a += dd * dv[s] * xsl[s];
                }
                scv = a + xsl[t] * dd * dd + bsp[0];
            }
            sco[t] = scv;
            idx[t] = (t < npg) ? t : 0x7fffffff;
        }
        __syncthreads();

        // ---- bitonic top-k sort by (-score, idx) ----
        for (int ksz = 2; ksz <= 256; ksz <<= 1) {
            for (int j = ksz >> 1; j > 0; j >>= 1) {
                int ixj = t ^ j;
                if (t < 256 && ixj > t) {
                    float s1 = sco[t], s2 = sco[ixj];
                    int i1 = idx[t], i2 = idx[ixj];
                    bool asc = ((t & ksz) == 0);
                    bool agtb = (s1 < s2) || (s1 == s2 && i1 > i2);
                    if (asc ? agtb : !agtb) { sco[t] = s2; sco[ixj] = s1; idx[t] = i2; idx[ixj] = i1; }
                }
                __syncthreads();
            }
        }
        if (t < kA) {
            rl[idx[t]] = t;
            ts[t] = tanhf(sco[t]);
        }
        __syncthreads();

        // ---- cml compose + pooling from acc regs into arena (stride 260) ----
        if (t < 256) {
            int old = cml[t];
            cml[t] = (old >= 0) ? rl[old] : -1;
        }
        #pragma unroll
        for (int rep = 0; rep < 2; rep++) {
            int mt = w + rep * 8;
            if (mt < MT) {
                #pragma unroll
                for (int r = 0; r < 4; r++) {
                    int rloc = mt * 16 + kgq * 4 + r;
                    int slot = (rloc < npg) ? rl[rloc] : -1;
                    if (slot >= 0) {
                        float tg = ts[slot];
                        #pragma unroll
                        for (int nt = 0; nt < 16; nt++)
                            arena[slot * 260 + nt * 16 + coll] = acc[rep][nt][r] * tg;
                    }
                }
            }
        }
        __syncthreads();

        // ---- readout gmp||gap into zlds ----
        if (t < 256) {
            float mx = -INFINITY, sm = 0.f;
            for (int j = 0; j < kA; j++) {
                float hv = arena[j * 260 + t];
                mx = fmaxf(mx, hv); sm += hv;
            }
            zlds[t] += mx;
            zlds[256 + t] += sm / (float)kA;
        }
        __syncthreads();
    }

    // ---- MLP head + log_softmax (reuse xsl as h1, sco as h2) ----
    float* h1 = xsl;
    float* h2 = sco;
    if (t < 256) {
        float a = bl1[t];
        for (int k = 0; k < 512; k++) a += zlds[k] * Wl1[k * 256 + t];
        h1[t] = fmaxf(a, 0.f);
    }
    __syncthreads();
    if (t < 128) {
        float a = bl2[t];
        for (int k = 0; k < 256; k++) a += h1[k] * Wl2[k * 128 + t];
        h2[t] = fmaxf(a, 0.f);
    }
    __syncthreads();
    if (t < 64) {
        float a0 = h2[t], a1 = h2[t + 64];
        float r[10];
        #pragma unroll
        for (int n = 0; n < 10; n++) r[n] = a0 * Wl3[t * 10 + n] + a1 * Wl3[(t + 64) * 10 + n];
        #pragma unroll
        for (int d = 1; d < 64; d <<= 1)
            #pragma unroll
            for (int n = 0; n < 10; n++) r[n] += __shfl_xor(r[n], d);
        float vv[10]; float mxv = -INFINITY;
        #pragma unroll
        for (int n = 0; n < 10; n++) { vv[n] = r[n] + bl3[n]; mxv = fmaxf(mxv, vv[n]); }
        float s = 0.f;
        #pragma unroll
        for (int n = 0; n < 10; n++) s += expf(vv[n] - mxv);
        float ls = logf(s);
        if (t < 10) out[g * 10 + t] = vv[t] - mxv - ls;
    }
}

extern "C" void kernel_launch(void* const* d_in, const int* in_sizes, int n_in,
                              void* d_out, int out_size, void* d_ws, size_t ws_size,
                              hipStream_t stream) {
    const float* x   = (const float*)d_in[0];
    const int*  esrc = (const int*) d_in[1];
    const int*  edst = (const int*) d_in[2];
    const float *W1 = (const float*)d_in[3],  *b1 = (const float*)d_in[4];
    const float *Ws1= (const float*)d_in[5],  *bs1= (const float*)d_in[6];
    const float *W2 = (const float*)d_in[7],  *b2 = (const float*)d_in[8];
    const float *Ws2= (const float*)d_in[9],  *bs2= (const float*)d_in[10];
    const float *W3 = (const float*)d_in[11], *b3 = (const float*)d_in[12];
    const float *Ws3= (const float*)d_in[13], *bs3= (const float*)d_in[14];
    const float *Wl1= (const float*)d_in[15], *bl1= (const float*)d_in[16];
    const float *Wl2= (const float*)d_in[17], *bl2= (const float*)d_in[18];
    const float *Wl3= (const float*)d_in[19], *bl3= (const float*)d_in[20];
    float* out = (float*)d_out;

    bf16* WTH = (bf16*)d_ws;                 // 3 * 256*256 bf16
    bf16* WTL = WTH + 3 * 65536;             // 3 * 256*256 bf16

    // 1. weight convert (all 3 stages)
    wconv_k<<<dim3(8, 8, 3), 256, 0, stream>>>(W1, W2, W3, WTH, WTL);

    // 2. whole network, one block per graph
    mega_k<<<B_, 512, LDS_TOTAL, stream>>>(
        x, esrc, edst, WTH, WTL,
        b1, b2, b3, Ws1, Ws2, Ws3, bs1, bs2, bs3,
        Wl1, bl1, Wl2, bl2, Wl3, bl3, out);
}